// Round 7
// baseline (180.944 us; speedup 1.0000x reference)
//
#include <hip/hip_runtime.h>

#define NN 4096
#define DD 2048
#define MARGIN_F 0.3f
#define NWT 2080   // 64x64 wave-tiles on the upper triangle (j >= i), 64*65/2
#define NBLK 520   // 4 wave-tiles per 256-thread block
#define QS (127.0f / 6.0f)
#define C2 (2.0f * (6.0f / 127.0f) * (6.0f / 127.0f))  // 2/QS^2

typedef __attribute__((ext_vector_type(4))) int i32x4;

__device__ __forceinline__ unsigned q8(float v) {
    int i = __float2int_rn(v * QS);
    i = min(127, max(-127, i));
    return (unsigned)(i & 255);
}

// 1024 blocks x 4 waves; each wave quantizes one row (int8) + fp32
// sum-of-squares; init ap/an/counter.
__global__ __launch_bounds__(256) void prep_kernel(const float* __restrict__ x,
                                                   unsigned char* __restrict__ xq,
                                                   float* __restrict__ sq,
                                                   unsigned int* __restrict__ ap,
                                                   unsigned int* __restrict__ an,
                                                   int* __restrict__ counter) {
    const int wave = threadIdx.x >> 6, lane = threadIdx.x & 63;
    const int row = blockIdx.x * 4 + wave;
    const float* xr = x + (size_t)row * DD;
    unsigned int* orow = (unsigned int*)(xq + (size_t)row * DD);
    float s = 0.0f;
#pragma unroll
    for (int j = 0; j < 8; ++j) {
        float4 v = ((const float4*)xr)[j * 64 + lane];
        s += v.x * v.x + v.y * v.y + v.z * v.z + v.w * v.w;
        orow[j * 64 + lane] = q8(v.x) | (q8(v.y) << 8) | (q8(v.z) << 16) | (q8(v.w) << 24);
    }
    for (int off = 32; off > 0; off >>= 1) s += __shfl_down(s, off, 64);
    if (lane == 0) {
        sq[row] = s;
        ap[row] = 0u;            // hardest-positive max starts at 0
        an[row] = 0x7F800000u;   // +inf
    }
    if (threadIdx.x == 0 && blockIdx.x == 0) counter[0] = 0;
}

// Symmetric batch-hard GEMM, int8. R7: BARRIER-FREE WAVE-STREAMING.
// R0-R6 post-mortems: MFMA busy is ~7 us in every variant; runtime is
// the stage->drain-barrier->ds_read machine (best effective staging
// rate 9 B/cyc/CU vs 21+ B/cyc/CU in streaming kernels on this chip).
// So delete the machine: each WAVE independently owns a 64x64 output
// tile (2080 tiles, j>=i), streams A/B fragments global->VGPR with
// global_load_dwordx4 (kc*64 offsets fold into 13-bit immediates) and
// MFMAs. No __syncthreads, no LDS, no cross-wave coupling: full-unroll
// k-loop lets the compiler hoist loads deep (launch_bounds(256,2) ->
// ~250 VGPR budget vs ~130 used); 2-3 resident waves/SIMD desync
// naturally; all 2080 waves co-resident (2.03/SIMD avg). Each 64-B
// line is fully consumed by one wave-instr (4 q-lanes x 16 B) -> no
// over-fetch. Fragment byte-map identical to validated R0 kernel
// (row*2048 + kc*64 + q*16) -> bitwise-identical acc.
// C/D: row = q*4+reg (A-operand rows), col = c (B-operand rows).
// Both-side epilogues per wave (idempotent max/min, gi!=gj guards the
// diagonal); fused last-block finalize.
__global__ __launch_bounds__(256, 2) void gemm_reduce_kernel(
    const unsigned char* __restrict__ xq,
    const float* __restrict__ sq,
    const int* __restrict__ labels,
    unsigned int* __restrict__ ap,
    unsigned int* __restrict__ an,
    int* __restrict__ counter,
    float* __restrict__ out) {
    __shared__ float ssum[4];
    __shared__ int scnt[4];
    __shared__ int flag;

    const int t = threadIdx.x;
    const int lane = t & 63;
    const int wave = t >> 6;
    const int c = lane & 15;   // fragment column lane
    const int q = lane >> 4;   // k-quad

    // wave-tile decode: wid -> (ti, tj), tj >= ti, count for ti is 64-ti.
    const int wid = blockIdx.x * 4 + wave;
    int rem = wid;
    int ti = 0;
    while (rem >= 64 - ti) { rem -= 64 - ti; ++ti; }
    const int tj = ti + rem;
    const int row0 = ti * 64;
    const int col0 = tj * 64;

    // Per-lane fragment pointers. A-frag for (mi,kc): row row0+mi*16+c,
    // bytes [kc*64 + q*16, +16). B-frag for (nj,kc): row col0+nj*16+c.
    const unsigned char* pA[4];
    const unsigned char* pB[4];
#pragma unroll
    for (int mi = 0; mi < 4; ++mi)
        pA[mi] = xq + (size_t)(row0 + mi * 16 + c) * DD + q * 16;
#pragma unroll
    for (int nj = 0; nj < 4; ++nj)
        pB[nj] = xq + (size_t)(col0 + nj * 16 + c) * DD + q * 16;

    i32x4 acc[4][4];
#pragma unroll
    for (int mi = 0; mi < 4; ++mi)
#pragma unroll
        for (int nj = 0; nj < 4; ++nj)
            acc[mi][nj] = (i32x4){0, 0, 0, 0};

    // Streaming K-loop: 32 k-chunks, 8 loads + 16 MFMA each, fully
    // unrolled; no barriers anywhere -> compiler pipelines loads ahead.
#pragma unroll
    for (int kc = 0; kc < 32; ++kc) {
        i32x4 af[4], bf[4];
#pragma unroll
        for (int mi = 0; mi < 4; ++mi)
            af[mi] = *(const i32x4*)(pA[mi] + (kc << 6));
#pragma unroll
        for (int nj = 0; nj < 4; ++nj)
            bf[nj] = *(const i32x4*)(pB[nj] + (kc << 6));
#pragma unroll
        for (int mi = 0; mi < 4; ++mi)
#pragma unroll
            for (int nj = 0; nj < 4; ++nj)
                acc[mi][nj] = __builtin_amdgcn_mfma_i32_16x16x64_i8(
                    af[mi], bf[nj], acc[mi][nj], 0, 0, 0);
    }

    // --- Epilogue (per wave, independent) ---
    // C/D layout 16x16: col = lane&15 (c), row = q*4 + reg [m89/m91;
    // dtype-independent m121-m128]
    float sq_col[4];
    int lab_col[4];
#pragma unroll
    for (int nj = 0; nj < 4; ++nj) {
        const int gj = col0 + nj * 16 + c;
        sq_col[nj] = sq[gj];
        lab_col[nj] = labels[gj];
    }
    int lab_row[4][4];
    float dist[4][4][4];  // [mi][nj][r]
#pragma unroll
    for (int mi = 0; mi < 4; ++mi) {
#pragma unroll
        for (int r = 0; r < 4; ++r) {
            const int gi = row0 + mi * 16 + q * 4 + r;
            const float sqi = sq[gi];
            lab_row[mi][r] = labels[gi];
#pragma unroll
            for (int nj = 0; nj < 4; ++nj) {
                float d2 = sqi + sq_col[nj] - C2 * (float)acc[mi][nj][r];
                dist[mi][nj][r] = sqrtf(fmaxf(d2, 0.0f));
            }
        }
    }

    // Row-side: rows gi vs this wave's 64 columns.
#pragma unroll
    for (int mi = 0; mi < 4; ++mi) {
#pragma unroll
        for (int r = 0; r < 4; ++r) {
            const int gi = row0 + mi * 16 + q * 4 + r;
            const int li = lab_row[mi][r];
            float apm = 0.0f;
            float anm = __builtin_inff();
#pragma unroll
            for (int nj = 0; nj < 4; ++nj) {
                const int gj = col0 + nj * 16 + c;
                const float d = dist[mi][nj][r];
                if (li == lab_col[nj]) {
                    if (gi != gj) apm = fmaxf(apm, d);  // exclude diagonal
                } else {
                    anm = fminf(anm, d);
                }
            }
#pragma unroll
            for (int off = 1; off < 16; off <<= 1) {
                apm = fmaxf(apm, __shfl_xor(apm, off, 16));
                anm = fminf(anm, __shfl_xor(anm, off, 16));
            }
            if (c == 0) {
                atomicMax(&ap[gi], __float_as_uint(apm));
                atomicMin(&an[gi], __float_as_uint(anm));
            }
        }
    }

    // Column-side (transposed): S(gi,gj) also serves row gj (dupes
    // idempotent; diagonal guarded).
#pragma unroll
    for (int nj = 0; nj < 4; ++nj) {
        const int gj = col0 + nj * 16 + c;
        const int lj = lab_col[nj];
        float apm = 0.0f;
        float anm = __builtin_inff();
#pragma unroll
        for (int mi = 0; mi < 4; ++mi) {
#pragma unroll
            for (int r = 0; r < 4; ++r) {
                const int gi = row0 + mi * 16 + q * 4 + r;
                const float d = dist[mi][nj][r];
                if (lj == lab_row[mi][r]) {
                    if (gi != gj) apm = fmaxf(apm, d);  // exclude diagonal
                } else {
                    anm = fminf(anm, d);
                }
            }
        }
        apm = fmaxf(apm, __shfl_xor(apm, 16, 64));
        anm = fminf(anm, __shfl_xor(anm, 16, 64));
        apm = fmaxf(apm, __shfl_xor(apm, 32, 64));
        anm = fminf(anm, __shfl_xor(anm, 32, 64));
        if (q == 0) {
            atomicMax(&ap[gj], __float_as_uint(apm));
            atomicMin(&an[gj], __float_as_uint(anm));
        }
    }

    // --- Fused finalize: last block to finish reduces the loss ---
    __syncthreads();  // drains this block's atomics before counter release
    if (t == 0) {
        int old = __hip_atomic_fetch_add(counter, 1, __ATOMIC_ACQ_REL,
                                         __HIP_MEMORY_SCOPE_AGENT);
        flag = (old == NBLK - 1) ? 1 : 0;
    }
    __syncthreads();
    if (flag) {
        float sum = 0.0f;
        int cnt = 0;
        for (int i = t; i < NN; i += 256) {
            const float a = __uint_as_float(__hip_atomic_load(
                &ap[i], __ATOMIC_RELAXED, __HIP_MEMORY_SCOPE_AGENT));
            const float b = __uint_as_float(__hip_atomic_load(
                &an[i], __ATOMIC_RELAXED, __HIP_MEMORY_SCOPE_AGENT));
            if ((a > 0.0f) && (b < __builtin_inff())) {
                sum += fmaxf(a - b + MARGIN_F, 0.0f);
                cnt += 1;
            }
        }
        for (int off = 32; off > 0; off >>= 1) {
            sum += __shfl_down(sum, off, 64);
            cnt += __shfl_down(cnt, off, 64);
        }
        if (lane == 0) { ssum[wave] = sum; scnt[wave] = cnt; }
        __syncthreads();
        if (t == 0) {
            float s = 0.0f; int n = 0;
#pragma unroll
            for (int w = 0; w < 4; ++w) { s += ssum[w]; n += scnt[w]; }
            out[0] = (n > 0) ? s / (float)n : 0.0f;
        }
    }
}

extern "C" void kernel_launch(void* const* d_in, const int* in_sizes, int n_in,
                              void* d_out, int out_size, void* d_ws, size_t ws_size,
                              hipStream_t stream) {
    const float* x = (const float*)d_in[0];
    const int* labels = (const int*)d_in[1];
    float* out = (float*)d_out;

    char* ws = (char*)d_ws;
    unsigned char* xq = (unsigned char*)ws;                         // 4096*2048 B
    float* sq = (float*)(ws + (size_t)NN * DD);
    unsigned int* ap = (unsigned int*)(ws + (size_t)NN * DD + (size_t)NN * 4);
    unsigned int* an = (unsigned int*)(ws + (size_t)NN * DD + (size_t)NN * 8);
    int* counter = (int*)(ws + (size_t)NN * DD + (size_t)NN * 12);

    prep_kernel<<<NN / 4, 256, 0, stream>>>(x, xq, sq, ap, an, counter);
    gemm_reduce_kernel<<<NBLK, 256, 0, stream>>>(xq, sq, labels, ap, an, counter, out);
}

// Round 8
// 150.325 us; speedup vs baseline: 1.2037x; 1.2037x over previous
//
#include <hip/hip_runtime.h>

#define NN 4096
#define DD 2048
#define MARGIN_F 0.3f
#define NTILES 528   // 128x128 tiles covering the upper triangle (nj >= mi)
#define BK 256       // K bytes per stage
#define NIT (DD / BK)  // 8
#define QS (127.0f / 6.0f)
#define C2 (2.0f * (6.0f / 127.0f) * (6.0f / 127.0f))  // 2/QS^2

typedef __attribute__((ext_vector_type(4))) int i32x4;

__device__ __forceinline__ unsigned q8(float v) {
    int i = __float2int_rn(v * QS);
    i = min(127, max(-127, i));
    return (unsigned)(i & 255);
}

// 1024 blocks x 4 waves; each wave quantizes one row (int8) + fp32
// sum-of-squares; init ap/an/counter.
__global__ __launch_bounds__(256) void prep_kernel(const float* __restrict__ x,
                                                   unsigned char* __restrict__ xq,
                                                   float* __restrict__ sq,
                                                   unsigned int* __restrict__ ap,
                                                   unsigned int* __restrict__ an,
                                                   int* __restrict__ counter) {
    const int wave = threadIdx.x >> 6, lane = threadIdx.x & 63;
    const int row = blockIdx.x * 4 + wave;
    const float* xr = x + (size_t)row * DD;
    unsigned int* orow = (unsigned int*)(xq + (size_t)row * DD);
    float s = 0.0f;
#pragma unroll
    for (int j = 0; j < 8; ++j) {
        float4 v = ((const float4*)xr)[j * 64 + lane];
        s += v.x * v.x + v.y * v.y + v.z * v.z + v.w * v.w;
        orow[j * 64 + lane] = q8(v.x) | (q8(v.y) << 8) | (q8(v.z) << 16) | (q8(v.w) << 24);
    }
    for (int off = 32; off > 0; off >>= 1) s += __shfl_down(s, off, 64);
    if (lane == 0) {
        sq[row] = s;
        ap[row] = 0u;            // hardest-positive max starts at 0
        an[row] = 0x7F800000u;   // +inf
    }
    if (threadIdx.x == 0 && blockIdx.x == 0) counter[0] = 0;
}

// Symmetric batch-hard GEMM, int8. R8: STAGED-BYTES REDUCTION.
// R0-R7 post-mortem: every structure (drain barriers / counted vmcnt /
// dbuf / full co-residency / LDS-free streaming) lands at 5-9.2 B/cyc/CU
// staged-byte throughput = ~5.7 TB/s aggregate, the HBM-class fabric
// ceiling (dataset 8 MB > 4 MB per-XCD L2 -> staging served by the
// L3/fabric path; R7's barrier-free variant proves it's a shared-pipe
// saturation, not kernel structure). So the gemm is OPERAND-BYTES-bound:
// bytes = (N^2*K/2)(1/TM + 1/TN). This kernel = R0's champion recipe
// (BK=256, NIT=8, single-buffer LDS, plain drain __syncthreads, 8-phase
// K-stagger, natural dispatch order) scaled to 128x128 tiles / 8 waves:
// 405 -> 276 MB staged (-32%). 528 blocks, 64 KB LDS -> 2 blocks/CU.
// 16-chunk rows keep col' = col ^ (row&15) swizzle (2-way = free, PMC=0).
// Wave grid 2x4: wave owns 64x32 sub-tile (4x2 frags), 32 MFMA/iter.
// Both-side epilogues (idempotent max/min, gi!=gj guards the diagonal);
// fused last-block finalize.
__global__ __launch_bounds__(512) void gemm_reduce_kernel(
    const unsigned char* __restrict__ xq,
    const float* __restrict__ sq,
    const int* __restrict__ labels,
    unsigned int* __restrict__ ap,
    unsigned int* __restrict__ an,
    int* __restrict__ counter,
    float* __restrict__ out) {
    __shared__ __align__(16) unsigned char As[128 * BK];   // 32 KB
    __shared__ __align__(16) unsigned char Bs[128 * BK];   // 32 KB

    // decode tile: (mi, nj) upper triangle, nj >= mi, 128-row x 128-col
    // panels; count for a given mi is 32 - mi. Natural dispatch order.
    int rem = blockIdx.x;
    int mi = 0;
    while (rem >= 32 - mi) { rem -= 32 - mi; ++mi; }
    const int nj = mi + rem;
    const int row0 = mi * 128;
    const int col0 = nj * 128;
    const int phase = blockIdx.x & (NIT - 1);  // K-start stagger (8 offsets)

    const int t = threadIdx.x;
    const int lane = t & 63;
    const int wave = t >> 6;           // 0..7
    const int c = lane & 15;           // fragment column lane
    const int q = lane >> 4;           // k-quad
    const int wrow = (wave >> 2) * 64; // wave row offset (2 row-halves)
    const int wcol = (wave & 3) * 32;  // wave col offset (4 col-quarters)

    i32x4 acc[4][2];
#pragma unroll
    for (int mm = 0; mm < 4; ++mm)
#pragma unroll
        for (int ni = 0; ni < 2; ++ni)
            acc[mm][ni] = (i32x4){0, 0, 0, 0};

    // Staging: rows are 256 B = 16 chunks of 16 B. Each tile (A or B) is
    // 128 rows = 2048 chunks; 512 threads -> 4 chunks/thread/tile.
    // Chunk ci = t + 512*s: row = ci>>4 = (t>>4) + 32*s, col = t&15;
    // source col XOR-swizzled: col ^ (row&15); row&15 = (t>>4)&15 is
    // s-invariant (32s = 0 mod 16), so one swizzled col per thread.
    const int rowb = t >> 4;
    const int colsw = (t & 15) ^ (rowb & 15);
    const unsigned char* gA[4];
    const unsigned char* gB[4];
#pragma unroll
    for (int s = 0; s < 4; ++s) {
        gA[s] = xq + (size_t)(row0 + rowb + 32 * s) * DD + colsw * 16;
        gB[s] = xq + (size_t)(col0 + rowb + 32 * s) * DD + colsw * 16;
    }

    for (int it = 0; it < NIT; ++it) {
        const int k0 = ((it + phase) & (NIT - 1)) * BK;
#pragma unroll
        for (int s = 0; s < 4; ++s)
            __builtin_amdgcn_global_load_lds(
                (const __attribute__((address_space(1))) void*)(gA[s] + k0),
                (__attribute__((address_space(3))) void*)&As[(t + 512 * s) * 16],
                16, 0, 0);
#pragma unroll
        for (int s = 0; s < 4; ++s)
            __builtin_amdgcn_global_load_lds(
                (const __attribute__((address_space(1))) void*)(gB[s] + k0),
                (__attribute__((address_space(3))) void*)&Bs[(t + 512 * s) * 16],
                16, 0, 0);
        __syncthreads();

        const i32x4* Av = (const i32x4*)As;
        const i32x4* Bv = (const i32x4*)Bs;
#pragma unroll
        for (int ks = 0; ks < 4; ++ks) {
            const int kc = q + 4 * ks;  // k-chunk for this lane's fragment
            i32x4 af[4], bfr[2];
#pragma unroll
            for (int mm = 0; mm < 4; ++mm) {
                const int r = wrow + mm * 16 + c;
                af[mm] = Av[r * 16 + (kc ^ (r & 15))];
            }
#pragma unroll
            for (int ni = 0; ni < 2; ++ni) {
                const int r = wcol + ni * 16 + c;
                bfr[ni] = Bv[r * 16 + (kc ^ (r & 15))];
            }
#pragma unroll
            for (int mm = 0; mm < 4; ++mm)
#pragma unroll
                for (int ni = 0; ni < 2; ++ni)
                    acc[mm][ni] = __builtin_amdgcn_mfma_i32_16x16x64_i8(
                        af[mm], bfr[ni], acc[mm][ni], 0, 0, 0);
        }
        __syncthreads();
    }

    // --- Epilogue ---
    // C/D layout 16x16: col = lane&15 (c), row = q*4 + reg [m89/m91;
    // dtype-independent m121-m128]
    float sq_col[2];
    int lab_col[2];
#pragma unroll
    for (int ni = 0; ni < 2; ++ni) {
        const int gj = col0 + wcol + ni * 16 + c;
        sq_col[ni] = sq[gj];
        lab_col[ni] = labels[gj];
    }
    int lab_row[4][4];
    float dist[4][2][4];
#pragma unroll
    for (int mm = 0; mm < 4; ++mm) {
#pragma unroll
        for (int r = 0; r < 4; ++r) {
            const int gi = row0 + wrow + mm * 16 + q * 4 + r;
            const float sqi = sq[gi];
            lab_row[mm][r] = labels[gi];
#pragma unroll
            for (int ni = 0; ni < 2; ++ni) {
                float d2 = sqi + sq_col[ni] - C2 * (float)acc[mm][ni][r];
                dist[mm][ni][r] = sqrtf(fmaxf(d2, 0.0f));
            }
        }
    }

    // Row-side: rows gi vs this wave's 32 columns.
#pragma unroll
    for (int mm = 0; mm < 4; ++mm) {
#pragma unroll
        for (int r = 0; r < 4; ++r) {
            const int gi = row0 + wrow + mm * 16 + q * 4 + r;
            const int li = lab_row[mm][r];
            float apm = 0.0f;
            float anm = __builtin_inff();
#pragma unroll
            for (int ni = 0; ni < 2; ++ni) {
                const int gj = col0 + wcol + ni * 16 + c;
                const float d = dist[mm][ni][r];
                if (li == lab_col[ni]) {
                    if (gi != gj) apm = fmaxf(apm, d);  // exclude diagonal
                } else {
                    anm = fminf(anm, d);
                }
            }
#pragma unroll
            for (int off = 1; off < 16; off <<= 1) {
                apm = fmaxf(apm, __shfl_xor(apm, off, 16));
                anm = fminf(anm, __shfl_xor(anm, off, 16));
            }
            if (c == 0) {
                atomicMax(&ap[gi], __float_as_uint(apm));
                atomicMin(&an[gi], __float_as_uint(anm));
            }
        }
    }

    // Column-side (transposed): S(gi,gj) also serves row gj (dupes
    // idempotent; diagonal guarded).
#pragma unroll
    for (int ni = 0; ni < 2; ++ni) {
        const int gj = col0 + wcol + ni * 16 + c;
        const int lj = lab_col[ni];
        float apm = 0.0f;
        float anm = __builtin_inff();
#pragma unroll
        for (int mm = 0; mm < 4; ++mm) {
#pragma unroll
            for (int r = 0; r < 4; ++r) {
                const int gi = row0 + wrow + mm * 16 + q * 4 + r;
                const float d = dist[mm][ni][r];
                if (lj == lab_row[mm][r]) {
                    if (gi != gj) apm = fmaxf(apm, d);  // exclude diagonal
                } else {
                    anm = fminf(anm, d);
                }
            }
        }
        apm = fmaxf(apm, __shfl_xor(apm, 16, 64));
        anm = fminf(anm, __shfl_xor(anm, 16, 64));
        apm = fmaxf(apm, __shfl_xor(apm, 32, 64));
        anm = fminf(anm, __shfl_xor(anm, 32, 64));
        if (q == 0) {
            atomicMax(&ap[gj], __float_as_uint(apm));
            atomicMin(&an[gj], __float_as_uint(anm));
        }
    }

    // --- Fused finalize: last block to finish reduces the loss ---
    __syncthreads();  // drains this block's atomics before counter release
    int* flag = (int*)As;
    if (t == 0) {
        int old = __hip_atomic_fetch_add(counter, 1, __ATOMIC_ACQ_REL,
                                         __HIP_MEMORY_SCOPE_AGENT);
        flag[0] = (old == NTILES - 1) ? 1 : 0;
    }
    __syncthreads();
    if (flag[0]) {
        float sum = 0.0f;
        int cnt = 0;
        for (int i = t; i < NN; i += 512) {
            const float a = __uint_as_float(__hip_atomic_load(
                &ap[i], __ATOMIC_RELAXED, __HIP_MEMORY_SCOPE_AGENT));
            const float b = __uint_as_float(__hip_atomic_load(
                &an[i], __ATOMIC_RELAXED, __HIP_MEMORY_SCOPE_AGENT));
            if ((a > 0.0f) && (b < __builtin_inff())) {
                sum += fmaxf(a - b + MARGIN_F, 0.0f);
                cnt += 1;
            }
        }
        for (int off = 32; off > 0; off >>= 1) {
            sum += __shfl_down(sum, off, 64);
            cnt += __shfl_down(cnt, off, 64);
        }
        float* ssum = (float*)Bs;
        int* scnt = (int*)Bs + 8;
        if (lane == 0) { ssum[wave] = sum; scnt[wave] = cnt; }
        __syncthreads();
        if (t == 0) {
            float s = 0.0f; int n = 0;
#pragma unroll
            for (int w = 0; w < 8; ++w) { s += ssum[w]; n += scnt[w]; }
            out[0] = (n > 0) ? s / (float)n : 0.0f;
        }
    }
}

extern "C" void kernel_launch(void* const* d_in, const int* in_sizes, int n_in,
                              void* d_out, int out_size, void* d_ws, size_t ws_size,
                              hipStream_t stream) {
    const float* x = (const float*)d_in[0];
    const int* labels = (const int*)d_in[1];
    float* out = (float*)d_out;

    char* ws = (char*)d_ws;
    unsigned char* xq = (unsigned char*)ws;                         // 4096*2048 B
    float* sq = (float*)(ws + (size_t)NN * DD);
    unsigned int* ap = (unsigned int*)(ws + (size_t)NN * DD + (size_t)NN * 4);
    unsigned int* an = (unsigned int*)(ws + (size_t)NN * DD + (size_t)NN * 8);
    int* counter = (int*)(ws + (size_t)NN * DD + (size_t)NN * 12);

    prep_kernel<<<NN / 4, 256, 0, stream>>>(x, xq, sq, ap, an, counter);
    gemm_reduce_kernel<<<NTILES, 512, 0, stream>>>(xq, sq, labels, ap, an, counter, out);
}

// Round 9
// 137.246 us; speedup vs baseline: 1.3184x; 1.0953x over previous
//
#include <hip/hip_runtime.h>

#define NN 4096
#define DD 2048
#define MARGIN_F 0.3f
#define NTILES 1056  // 64x128 tiles covering the upper triangle (dupes OK)
#define BK 256       // K bytes per stage
#define NIT (DD / BK)  // 8
#define QS (127.0f / 6.0f)
#define C2 (2.0f * (6.0f / 127.0f) * (6.0f / 127.0f))  // 2/QS^2

typedef __attribute__((ext_vector_type(4))) int i32x4;

__device__ __forceinline__ unsigned q8(float v) {
    int i = __float2int_rn(v * QS);
    i = min(127, max(-127, i));
    return (unsigned)(i & 255);
}

// 1024 blocks x 4 waves; each wave quantizes one row (int8) + fp32
// sum-of-squares; init ap/an/counter.
__global__ __launch_bounds__(256) void prep_kernel(const float* __restrict__ x,
                                                   unsigned char* __restrict__ xq,
                                                   float* __restrict__ sq,
                                                   unsigned int* __restrict__ ap,
                                                   unsigned int* __restrict__ an,
                                                   int* __restrict__ counter) {
    const int wave = threadIdx.x >> 6, lane = threadIdx.x & 63;
    const int row = blockIdx.x * 4 + wave;
    const float* xr = x + (size_t)row * DD;
    unsigned int* orow = (unsigned int*)(xq + (size_t)row * DD);
    float s = 0.0f;
#pragma unroll
    for (int j = 0; j < 8; ++j) {
        float4 v = ((const float4*)xr)[j * 64 + lane];
        s += v.x * v.x + v.y * v.y + v.z * v.z + v.w * v.w;
        orow[j * 64 + lane] = q8(v.x) | (q8(v.y) << 8) | (q8(v.z) << 16) | (q8(v.w) << 24);
    }
    for (int off = 32; off > 0; off >>= 1) s += __shfl_down(s, off, 64);
    if (lane == 0) {
        sq[row] = s;
        ap[row] = 0u;            // hardest-positive max starts at 0
        an[row] = 0x7F800000u;   // +inf
    }
    if (threadIdx.x == 0 && blockIdx.x == 0) counter[0] = 0;
}

// Symmetric batch-hard GEMM, int8. R9 = R0 verbatim (proven 72 us champ:
// 64x128 tiles, BK=256, NIT=8, single-buffer LDS, drain barriers,
// phase = blockIdx&7 K-stagger, 3 blocks/CU) + SUPER-BLOCK COMPACT
// SCHEDULING. R8 post-mortem: R0 stages 405 MB at 5.7 TB/s = the
// LLC/fabric ceiling (FETCH only 38 MB -> traffic is LLC-served, and
// 8 MB dataset > 4 MB L2/XCD so ~half misses L2). L2 itself = 37 TB/s.
// R5's XCD swizzle failed because triangle-ROW-order runs span ALL col
// panels (8 MB footprint). Fix: enumerate tiles by 512x512 SUPER-BLOCK
// (8x8 super-grid, 8 diag supers x20 tiles + 28 off-diag x32 = 1056);
// XCD x (= blockIdx&7 under round-robin dispatch) gets contiguous run
// [132x,132x+132) -> co-resident ~96 blocks sit in 1-2 supers ->
// footprint (512 rows + <=1024 cols) x 2048 B = 2-3 MB < 4 MB L2.
// Stagger compatible (footprint counts full rows, not K-slices).
// Everything else byte-identical to R0. Both-side epilogues; fused
// last-block finalize.
__global__ __launch_bounds__(256) void gemm_reduce_kernel(
    const unsigned char* __restrict__ xq,
    const float* __restrict__ sq,
    const int* __restrict__ labels,
    unsigned int* __restrict__ ap,
    unsigned int* __restrict__ an,
    int* __restrict__ counter,
    float* __restrict__ out) {
    __shared__ __align__(16) unsigned char As[64 * BK];    // 16 KB
    __shared__ __align__(16) unsigned char Bs[128 * BK];   // 32 KB

    // ---- super-block tile decode ----
    // g = position in super-order; XCD (orig&7) owns run [132x, 132x+132).
    const int orig = blockIdx.x;
    int g = (orig & 7) * (NTILES / 8) + (orig >> 3);
    // super row si: row si holds 244 - 32*si tiles (diag 20 + (7-si)*32).
    int si = 0, row_cnt = 244;
    while (g >= row_cnt) { g -= row_cnt; ++si; row_cnt -= 32; }
    int mi64, nj;
    if (g < 20) {  // diagonal super (si,si): 8 row-tiles x 4 col-tiles tri
        int ml = 0;
        while (g >= 4 - (ml >> 1)) { g -= 4 - (ml >> 1); ++ml; }
        mi64 = si * 8 + ml;
        nj = si * 4 + (ml >> 1) + g;
    } else {       // off-diagonal super (si, sj): full 8x4
        g -= 20;
        const int sj = si + 1 + (g >> 5);
        const int r = g & 31;
        mi64 = si * 8 + (r >> 2);
        nj = sj * 4 + (r & 3);
    }
    const int row0 = mi64 * 64;
    const int col0 = nj * 128;
    const int phase = orig & (NIT - 1);  // K-start stagger (as in R0)

    const int t = threadIdx.x;
    const int lane = t & 63;
    const int wave = t >> 6;
    const int c = lane & 15;   // fragment column lane
    const int q = lane >> 4;   // k-quad
    const int wc = wave * 32;  // wave col offset (rows shared by all waves)

    i32x4 acc[4][2];
#pragma unroll
    for (int mi = 0; mi < 4; ++mi)
#pragma unroll
        for (int ni = 0; ni < 2; ++ni)
            acc[mi][ni] = (i32x4){0, 0, 0, 0};

    // Staging: rows are 256 B = 16 chunks of 16 B. A tile 64 rows = 1024
    // chunks (4/thread), B tile 128 rows = 2048 chunks (8/thread).
    // Chunk ci = t + 256*s: row = ci>>4 = (t>>4) + 16*s, col = t&15;
    // source col XOR-swizzled: col ^ (row&15), and row&15 = (t>>4)&15 is
    // s-invariant, so one swizzled col per thread.
    const int rowb = t >> 4;
    const int colsw = (t & 15) ^ (rowb & 15);
    const unsigned char* gA[4];
    const unsigned char* gB[8];
#pragma unroll
    for (int s = 0; s < 4; ++s)
        gA[s] = xq + (size_t)(row0 + rowb + 16 * s) * DD + colsw * 16;
#pragma unroll
    for (int s = 0; s < 8; ++s)
        gB[s] = xq + (size_t)(col0 + rowb + 16 * s) * DD + colsw * 16;

    for (int it = 0; it < NIT; ++it) {
        const int k0 = ((it + phase) & (NIT - 1)) * BK;
#pragma unroll
        for (int s = 0; s < 4; ++s)
            __builtin_amdgcn_global_load_lds(
                (const __attribute__((address_space(1))) void*)(gA[s] + k0),
                (__attribute__((address_space(3))) void*)&As[(t + 256 * s) * 16],
                16, 0, 0);
#pragma unroll
        for (int s = 0; s < 8; ++s)
            __builtin_amdgcn_global_load_lds(
                (const __attribute__((address_space(1))) void*)(gB[s] + k0),
                (__attribute__((address_space(3))) void*)&Bs[(t + 256 * s) * 16],
                16, 0, 0);
        __syncthreads();

        const i32x4* Av = (const i32x4*)As;
        const i32x4* Bv = (const i32x4*)Bs;
#pragma unroll
        for (int ks = 0; ks < 4; ++ks) {
            const int kc = q + 4 * ks;  // k-chunk for this lane's fragment
            i32x4 af[4], bfr[2];
#pragma unroll
            for (int mi = 0; mi < 4; ++mi) {
                const int r = mi * 16 + c;
                af[mi] = Av[r * 16 + (kc ^ (r & 15))];
            }
#pragma unroll
            for (int ni = 0; ni < 2; ++ni) {
                const int r = wc + ni * 16 + c;
                bfr[ni] = Bv[r * 16 + (kc ^ (r & 15))];
            }
#pragma unroll
            for (int mi = 0; mi < 4; ++mi)
#pragma unroll
                for (int ni = 0; ni < 2; ++ni)
                    acc[mi][ni] = __builtin_amdgcn_mfma_i32_16x16x64_i8(
                        af[mi], bfr[ni], acc[mi][ni], 0, 0, 0);
        }
        __syncthreads();
    }

    // --- Epilogue ---
    // C/D layout 16x16: col = lane&15 (c), row = q*4 + reg [m89/m91;
    // dtype-independent m121-m128]
    float sq_col[2];
    int lab_col[2];
#pragma unroll
    for (int ni = 0; ni < 2; ++ni) {
        const int gj = col0 + wc + ni * 16 + c;
        sq_col[ni] = sq[gj];
        lab_col[ni] = labels[gj];
    }
    int lab_row[4][4];
    float dist[4][2][4];
#pragma unroll
    for (int mi = 0; mi < 4; ++mi) {
#pragma unroll
        for (int r = 0; r < 4; ++r) {
            const int gi = row0 + mi * 16 + q * 4 + r;
            const float sqi = sq[gi];
            lab_row[mi][r] = labels[gi];
#pragma unroll
            for (int ni = 0; ni < 2; ++ni) {
                float d2 = sqi + sq_col[ni] - C2 * (float)acc[mi][ni][r];
                dist[mi][ni][r] = sqrtf(fmaxf(d2, 0.0f));
            }
        }
    }

    // Row-side: rows gi vs this wave's 32 columns.
#pragma unroll
    for (int mi = 0; mi < 4; ++mi) {
#pragma unroll
        for (int r = 0; r < 4; ++r) {
            const int gi = row0 + mi * 16 + q * 4 + r;
            const int li = lab_row[mi][r];
            float apm = 0.0f;
            float anm = __builtin_inff();
#pragma unroll
            for (int ni = 0; ni < 2; ++ni) {
                const int gj = col0 + wc + ni * 16 + c;
                const float d = dist[mi][ni][r];
                if (li == lab_col[ni]) {
                    if (gi != gj) apm = fmaxf(apm, d);  // exclude diagonal
                } else {
                    anm = fminf(anm, d);
                }
            }
#pragma unroll
            for (int off = 1; off < 16; off <<= 1) {
                apm = fmaxf(apm, __shfl_xor(apm, off, 16));
                anm = fminf(anm, __shfl_xor(anm, off, 16));
            }
            if (c == 0) {
                atomicMax(&ap[gi], __float_as_uint(apm));
                atomicMin(&an[gi], __float_as_uint(anm));
            }
        }
    }

    // Column-side (transposed): S(gi,gj) also serves row gj (dupes
    // idempotent; diagonal guarded).
#pragma unroll
    for (int ni = 0; ni < 2; ++ni) {
        const int gj = col0 + wc + ni * 16 + c;
        const int lj = lab_col[ni];
        float apm = 0.0f;
        float anm = __builtin_inff();
#pragma unroll
        for (int mi = 0; mi < 4; ++mi) {
#pragma unroll
            for (int r = 0; r < 4; ++r) {
                const int gi = row0 + mi * 16 + q * 4 + r;
                const float d = dist[mi][ni][r];
                if (lj == lab_row[mi][r]) {
                    if (gi != gj) apm = fmaxf(apm, d);  // exclude diagonal
                } else {
                    anm = fminf(anm, d);
                }
            }
        }
        apm = fmaxf(apm, __shfl_xor(apm, 16, 64));
        anm = fminf(anm, __shfl_xor(anm, 16, 64));
        apm = fmaxf(apm, __shfl_xor(apm, 32, 64));
        anm = fminf(anm, __shfl_xor(anm, 32, 64));
        if (q == 0) {
            atomicMax(&ap[gj], __float_as_uint(apm));
            atomicMin(&an[gj], __float_as_uint(anm));
        }
    }

    // --- Fused finalize: last block to finish reduces the loss ---
    __syncthreads();  // drains this block's atomics before counter release
    int* flag = (int*)As;
    if (t == 0) {
        int old = __hip_atomic_fetch_add(counter, 1, __ATOMIC_ACQ_REL,
                                         __HIP_MEMORY_SCOPE_AGENT);
        flag[0] = (old == NTILES - 1) ? 1 : 0;
    }
    __syncthreads();
    if (flag[0]) {
        float sum = 0.0f;
        int cnt = 0;
        for (int i = t; i < NN; i += 256) {
            const float a = __uint_as_float(__hip_atomic_load(
                &ap[i], __ATOMIC_RELAXED, __HIP_MEMORY_SCOPE_AGENT));
            const float b = __uint_as_float(__hip_atomic_load(
                &an[i], __ATOMIC_RELAXED, __HIP_MEMORY_SCOPE_AGENT));
            if ((a > 0.0f) && (b < __builtin_inff())) {
                sum += fmaxf(a - b + MARGIN_F, 0.0f);
                cnt += 1;
            }
        }
        for (int off = 32; off > 0; off >>= 1) {
            sum += __shfl_down(sum, off, 64);
            cnt += __shfl_down(cnt, off, 64);
        }
        float* ssum = (float*)Bs;
        int* scnt = (int*)Bs + 8;
        if (lane == 0) { ssum[wave] = sum; scnt[wave] = cnt; }
        __syncthreads();
        if (t == 0) {
            float s = 0.0f; int n = 0;
#pragma unroll
            for (int w = 0; w < 4; ++w) { s += ssum[w]; n += scnt[w]; }
            out[0] = (n > 0) ? s / (float)n : 0.0f;
        }
    }
}

extern "C" void kernel_launch(void* const* d_in, const int* in_sizes, int n_in,
                              void* d_out, int out_size, void* d_ws, size_t ws_size,
                              hipStream_t stream) {
    const float* x = (const float*)d_in[0];
    const int* labels = (const int*)d_in[1];
    float* out = (float*)d_out;

    char* ws = (char*)d_ws;
    unsigned char* xq = (unsigned char*)ws;                         // 4096*2048 B
    float* sq = (float*)(ws + (size_t)NN * DD);
    unsigned int* ap = (unsigned int*)(ws + (size_t)NN * DD + (size_t)NN * 4);
    unsigned int* an = (unsigned int*)(ws + (size_t)NN * DD + (size_t)NN * 8);
    int* counter = (int*)(ws + (size_t)NN * DD + (size_t)NN * 12);

    prep_kernel<<<NN / 4, 256, 0, stream>>>(x, xq, sq, ap, an, counter);
    gemm_reduce_kernel<<<NTILES, 256, 0, stream>>>(xq, sq, labels, ap, an, counter, out);
}

// Round 10
// 135.825 us; speedup vs baseline: 1.3322x; 1.0105x over previous
//
#include <hip/hip_runtime.h>

#define NN 4096
#define DD 2048
#define MARGIN_F 0.3f
#define NTILES 1056  // 64x128 tiles covering the upper triangle (dupes OK)
#define BK 128       // K bytes per stage
#define NIT (DD / BK)  // 16
#define QS (127.0f / 6.0f)
#define C2 (2.0f * (6.0f / 127.0f) * (6.0f / 127.0f))  // 2/QS^2

typedef __attribute__((ext_vector_type(4))) int i32x4;

__device__ __forceinline__ unsigned q8(float v) {
    int i = __float2int_rn(v * QS);
    i = min(127, max(-127, i));
    return (unsigned)(i & 255);
}

// 1024 blocks x 4 waves; each wave quantizes one row (int8) + fp32
// sum-of-squares; init ap/an/counter.
__global__ __launch_bounds__(256) void prep_kernel(const float* __restrict__ x,
                                                   unsigned char* __restrict__ xq,
                                                   float* __restrict__ sq,
                                                   unsigned int* __restrict__ ap,
                                                   unsigned int* __restrict__ an,
                                                   int* __restrict__ counter) {
    const int wave = threadIdx.x >> 6, lane = threadIdx.x & 63;
    const int row = blockIdx.x * 4 + wave;
    const float* xr = x + (size_t)row * DD;
    unsigned int* orow = (unsigned int*)(xq + (size_t)row * DD);
    float s = 0.0f;
#pragma unroll
    for (int j = 0; j < 8; ++j) {
        float4 v = ((const float4*)xr)[j * 64 + lane];
        s += v.x * v.x + v.y * v.y + v.z * v.z + v.w * v.w;
        orow[j * 64 + lane] = q8(v.x) | (q8(v.y) << 8) | (q8(v.z) << 16) | (q8(v.w) << 24);
    }
    for (int off = 32; off > 0; off >>= 1) s += __shfl_down(s, off, 64);
    if (lane == 0) {
        sq[row] = s;
        ap[row] = 0u;            // hardest-positive max starts at 0
        an[row] = 0x7F800000u;   // +inf
    }
    if (threadIdx.x == 0 && blockIdx.x == 0) counter[0] = 0;
}

// Symmetric batch-hard GEMM, int8. R10 = R9's super-block L2 locality
// (proven: FETCH 38->23 MB, gemm 72->64 us) + R2's counted-vmcnt
// double-buffer pipeline (proven: per-seq-iter 5.8 -> 3.7 us). R9
// post-mortem: staged throughput stayed ~10 B/cyc/CU even at 94% L2-hit
// -> the floor is the serialized stage->drain->compute structure, which
// counted vmcnt attacks; R2's two failure causes (no locality: 900-cyc
// misses; no stagger) are both fixed here. BK=128, NIT=16, 48 KB LDS
// -> 3 blocks/CU. Stage 2 tiles ahead; per phase `s_waitcnt vmcnt(6)`
// (never 0 in-loop) + raw s_barrier; prefetch distance = 1 full
// iteration (~1300 cyc) >> L2-hit latency (~250 cyc).
// Super-block decode (R9 verbatim): 512x512 supers, XCD x = orig&7 owns
// contiguous run [132x,132x+132) -> footprint 2-3 MB < 4 MB L2.
// Stagger XCD-uniform, 256-B granule: phase=(orig&7)*2.
// 8-chunk rows use col' = col ^ (row&7) swizzle (conflict-free, PMC=0).
// mfma_i32_16x16x64_i8, wave = 64 rows x 32 cols (4x2 frags). Both-side
// epilogues (idempotent max/min, gi!=gj guards diagonal); fused
// last-block finalize.
__global__ __launch_bounds__(256) void gemm_reduce_kernel(
    const unsigned char* __restrict__ xq,
    const float* __restrict__ sq,
    const int* __restrict__ labels,
    unsigned int* __restrict__ ap,
    unsigned int* __restrict__ an,
    int* __restrict__ counter,
    float* __restrict__ out) {
    __shared__ __align__(16) unsigned char As0[64 * BK];    // 8 KB
    __shared__ __align__(16) unsigned char Bs0[128 * BK];   // 16 KB
    __shared__ __align__(16) unsigned char As1[64 * BK];    // 8 KB
    __shared__ __align__(16) unsigned char Bs1[128 * BK];   // 16 KB

    // ---- super-block tile decode (R9 verbatim) ----
    // g = position in super-order; XCD (orig&7) owns run [132x, 132x+132).
    const int orig = blockIdx.x;
    int g = (orig & 7) * (NTILES / 8) + (orig >> 3);
    // super row si: row si holds 244 - 32*si tiles (diag 20 + (7-si)*32).
    int si = 0, row_cnt = 244;
    while (g >= row_cnt) { g -= row_cnt; ++si; row_cnt -= 32; }
    int mi64, nj;
    if (g < 20) {  // diagonal super (si,si): 8 row-tiles x 4 col-tiles tri
        int ml = 0;
        while (g >= 4 - (ml >> 1)) { g -= 4 - (ml >> 1); ++ml; }
        mi64 = si * 8 + ml;
        nj = si * 4 + (ml >> 1) + g;
    } else {       // off-diagonal super (si, sj): full 8x4
        g -= 20;
        const int sj = si + 1 + (g >> 5);
        const int r = g & 31;
        mi64 = si * 8 + (r >> 2);
        nj = sj * 4 + (r & 3);
    }
    const int row0 = mi64 * 64;
    const int col0 = nj * 128;
    const int phase = (orig & 7) * 2;  // XCD-uniform stagger, 256-B granule

    const int t = threadIdx.x;
    const int lane = t & 63;
    const int wave = t >> 6;
    const int c = lane & 15;   // fragment column lane
    const int q = lane >> 4;   // k-quad
    const int wc = wave * 32;  // wave col offset (rows shared by all waves)

    i32x4 acc[4][2];
#pragma unroll
    for (int mi = 0; mi < 4; ++mi)
#pragma unroll
        for (int ni = 0; ni < 2; ++ni)
            acc[mi][ni] = (i32x4){0, 0, 0, 0};

    // Staging: rows are 128 B = 8 chunks of 16 B. A tile 64 rows = 512
    // chunks (2/thread), B tile 128 rows = 1024 chunks (4/thread).
    // Chunk ci = t + 256*s: row = ci>>3 = (t>>3) + 32*s, col = t&7;
    // source col XOR-swizzled: col ^ (row&7), and row&7 = (t>>3)&7 is
    // s-invariant, so one swizzled col per thread.
    const int rowb = t >> 3;
    const int colsw = (t & 7) ^ (rowb & 7);
    const unsigned char* gA[2];
    const unsigned char* gB[4];
#pragma unroll
    for (int s = 0; s < 2; ++s)
        gA[s] = xq + (size_t)(row0 + rowb + 32 * s) * DD + colsw * 16;
#pragma unroll
    for (int s = 0; s < 4; ++s)
        gB[s] = xq + (size_t)(col0 + rowb + 32 * s) * DD + colsw * 16;

    // 6 global_load_lds per thread per stage (per-wave vmcnt += 6).
    auto stage = [&](unsigned char* A, unsigned char* B, int it) {
        const int k0 = ((it + phase) & (NIT - 1)) * BK;
#pragma unroll
        for (int s = 0; s < 2; ++s)
            __builtin_amdgcn_global_load_lds(
                (const __attribute__((address_space(1))) void*)(gA[s] + k0),
                (__attribute__((address_space(3))) void*)&A[(t + 256 * s) * 16],
                16, 0, 0);
#pragma unroll
        for (int s = 0; s < 4; ++s)
            __builtin_amdgcn_global_load_lds(
                (const __attribute__((address_space(1))) void*)(gB[s] + k0),
                (__attribute__((address_space(3))) void*)&B[(t + 256 * s) * 16],
                16, 0, 0);
    };

    auto compute = [&](const unsigned char* A, const unsigned char* B) {
        const i32x4* Av = (const i32x4*)A;
        const i32x4* Bv = (const i32x4*)B;
#pragma unroll
        for (int ks = 0; ks < 2; ++ks) {
            const int kc = q + 4 * ks;  // k-chunk for this lane's fragment
            i32x4 af[4], bfr[2];
#pragma unroll
            for (int mi = 0; mi < 4; ++mi) {
                const int r = mi * 16 + c;
                af[mi] = Av[r * 8 + (kc ^ (r & 7))];
            }
#pragma unroll
            for (int ni = 0; ni < 2; ++ni) {
                const int r = wc + ni * 16 + c;
                bfr[ni] = Bv[r * 8 + (kc ^ (r & 7))];
            }
#pragma unroll
            for (int mi = 0; mi < 4; ++mi)
#pragma unroll
                for (int ni = 0; ni < 2; ++ni)
                    acc[mi][ni] = __builtin_amdgcn_mfma_i32_16x16x64_i8(
                        af[mi], bfr[ni], acc[mi][ni], 0, 0, 0);
        }
    };

    // Counted-vmcnt pipeline (R2 verbatim). Ledger (per wave, 6/stage):
    //   prologue: stage(0), stage(1)            -> 12 outstanding
    //   phase(it): vmcnt(6) waits stage(it) done (only stage(it+1)'s 6
    //   remain); s_barrier -> buf ready all waves; compute; fence +
    //   s_barrier -> all waves done READING buf; re-stage buf for it+2.
    //   Last phase vmcnt(0) (nothing behind it). No drain elsewhere.
    stage(As0, Bs0, 0);
    stage(As1, Bs1, 1);
#pragma unroll
    for (int it = 0; it < NIT; it += 2) {
        // ---- phase A: tile it in {As0,Bs0} ----
        asm volatile("s_waitcnt vmcnt(6)" ::: "memory");
        __builtin_amdgcn_s_barrier();
        compute(As0, Bs0);
        asm volatile("" ::: "memory");  // keep ds_reads above the barrier
        __builtin_amdgcn_s_barrier();
        if (it + 2 < NIT) stage(As0, Bs0, it + 2);
        // ---- phase B: tile it+1 in {As1,Bs1} ----
        if (it + 2 < NIT)
            asm volatile("s_waitcnt vmcnt(6)" ::: "memory");
        else
            asm volatile("s_waitcnt vmcnt(0)" ::: "memory");
        __builtin_amdgcn_s_barrier();
        compute(As1, Bs1);
        asm volatile("" ::: "memory");
        __builtin_amdgcn_s_barrier();
        if (it + 3 < NIT) stage(As1, Bs1, it + 3);
    }

    // --- Epilogue ---
    // C/D layout 16x16: col = lane&15 (c), row = q*4 + reg [m89/m91;
    // dtype-independent m121-m128]
    float sq_col[2];
    int lab_col[2];
#pragma unroll
    for (int ni = 0; ni < 2; ++ni) {
        const int gj = col0 + wc + ni * 16 + c;
        sq_col[ni] = sq[gj];
        lab_col[ni] = labels[gj];
    }
    int lab_row[4][4];
    float dist[4][2][4];
#pragma unroll
    for (int mi = 0; mi < 4; ++mi) {
#pragma unroll
        for (int r = 0; r < 4; ++r) {
            const int gi = row0 + mi * 16 + q * 4 + r;
            const float sqi = sq[gi];
            lab_row[mi][r] = labels[gi];
#pragma unroll
            for (int ni = 0; ni < 2; ++ni) {
                float d2 = sqi + sq_col[ni] - C2 * (float)acc[mi][ni][r];
                dist[mi][ni][r] = sqrtf(fmaxf(d2, 0.0f));
            }
        }
    }

    // Row-side: rows gi vs this wave's 32 columns.
#pragma unroll
    for (int mi = 0; mi < 4; ++mi) {
#pragma unroll
        for (int r = 0; r < 4; ++r) {
            const int gi = row0 + mi * 16 + q * 4 + r;
            const int li = lab_row[mi][r];
            float apm = 0.0f;
            float anm = __builtin_inff();
#pragma unroll
            for (int ni = 0; ni < 2; ++ni) {
                const int gj = col0 + wc + ni * 16 + c;
                const float d = dist[mi][ni][r];
                if (li == lab_col[ni]) {
                    if (gi != gj) apm = fmaxf(apm, d);  // exclude diagonal
                } else {
                    anm = fminf(anm, d);
                }
            }
#pragma unroll
            for (int off = 1; off < 16; off <<= 1) {
                apm = fmaxf(apm, __shfl_xor(apm, off, 16));
                anm = fminf(anm, __shfl_xor(anm, off, 16));
            }
            if (c == 0) {
                atomicMax(&ap[gi], __float_as_uint(apm));
                atomicMin(&an[gi], __float_as_uint(anm));
            }
        }
    }

    // Column-side (transposed): S(gi,gj) also serves row gj (dupes
    // idempotent; diagonal guarded).
#pragma unroll
    for (int ni = 0; ni < 2; ++ni) {
        const int gj = col0 + wc + ni * 16 + c;
        const int lj = lab_col[ni];
        float apm = 0.0f;
        float anm = __builtin_inff();
#pragma unroll
        for (int mi = 0; mi < 4; ++mi) {
#pragma unroll
            for (int r = 0; r < 4; ++r) {
                const int gi = row0 + mi * 16 + q * 4 + r;
                const float d = dist[mi][ni][r];
                if (lj == lab_row[mi][r]) {
                    if (gi != gj) apm = fmaxf(apm, d);  // exclude diagonal
                } else {
                    anm = fminf(anm, d);
                }
            }
        }
        apm = fmaxf(apm, __shfl_xor(apm, 16, 64));
        anm = fminf(anm, __shfl_xor(anm, 16, 64));
        apm = fmaxf(apm, __shfl_xor(apm, 32, 64));
        anm = fminf(anm, __shfl_xor(anm, 32, 64));
        if (q == 0) {
            atomicMax(&ap[gj], __float_as_uint(apm));
            atomicMin(&an[gj], __float_as_uint(anm));
        }
    }

    // --- Fused finalize: last block to finish reduces the loss ---
    __syncthreads();  // drains this block's atomics before counter release
    int* flag = (int*)As0;
    if (t == 0) {
        int old = __hip_atomic_fetch_add(counter, 1, __ATOMIC_ACQ_REL,
                                         __HIP_MEMORY_SCOPE_AGENT);
        flag[0] = (old == NTILES - 1) ? 1 : 0;
    }
    __syncthreads();
    if (flag[0]) {
        float sum = 0.0f;
        int cnt = 0;
        for (int i = t; i < NN; i += 256) {
            const float a = __uint_as_float(__hip_atomic_load(
                &ap[i], __ATOMIC_RELAXED, __HIP_MEMORY_SCOPE_AGENT));
            const float b = __uint_as_float(__hip_atomic_load(
                &an[i], __ATOMIC_RELAXED, __HIP_MEMORY_SCOPE_AGENT));
            if ((a > 0.0f) && (b < __builtin_inff())) {
                sum += fmaxf(a - b + MARGIN_F, 0.0f);
                cnt += 1;
            }
        }
        for (int off = 32; off > 0; off >>= 1) {
            sum += __shfl_down(sum, off, 64);
            cnt += __shfl_down(cnt, off, 64);
        }
        float* ssum = (float*)Bs0;
        int* scnt = (int*)Bs0 + 8;
        if (lane == 0) { ssum[wave] = sum; scnt[wave] = cnt; }
        __syncthreads();
        if (t == 0) {
            float s = 0.0f; int n = 0;
#pragma unroll
            for (int w = 0; w < 4; ++w) { s += ssum[w]; n += scnt[w]; }
            out[0] = (n > 0) ? s / (float)n : 0.0f;
        }
    }
}

extern "C" void kernel_launch(void* const* d_in, const int* in_sizes, int n_in,
                              void* d_out, int out_size, void* d_ws, size_t ws_size,
                              hipStream_t stream) {
    const float* x = (const float*)d_in[0];
    const int* labels = (const int*)d_in[1];
    float* out = (float*)d_out;

    char* ws = (char*)d_ws;
    unsigned char* xq = (unsigned char*)ws;                         // 4096*2048 B
    float* sq = (float*)(ws + (size_t)NN * DD);
    unsigned int* ap = (unsigned int*)(ws + (size_t)NN * DD + (size_t)NN * 4);
    unsigned int* an = (unsigned int*)(ws + (size_t)NN * DD + (size_t)NN * 8);
    int* counter = (int*)(ws + (size_t)NN * DD + (size_t)NN * 12);

    prep_kernel<<<NN / 4, 256, 0, stream>>>(x, xq, sq, ap, an, counter);
    gemm_reduce_kernel<<<NTILES, 256, 0, stream>>>(xq, sq, labels, ap, an, counter, out);
}